// Round 3
// baseline (416.954 us; speedup 1.0000x reference)
//
#include <hip/hip_runtime.h>

// RoIAlign forward, MI355X (gfx950).
// features: (2, 256, 200, 200) fp32, NCHW
// rois:     (N=1000, 5) fp32  [batch, x1, y1, x2, y2] image coords, scale 0.25
// out:      (N, 256, 7, 7) fp32
//
// Mapping: grid = (49, N), block = 256. Thread t of roi n computes output
// element n*12544 + (blockIdx.x*256 + t); c = e/49, bin = e%49.
// - roi index n = blockIdx.y is uniform -> roi fields scalarize to s_load +
//   SGPR math (no per-lane roi traffic, fewer VGPRs).
// - bin fastest across lanes -> coalesced stores; adjacent bins' samples are
//   ~tens of bytes apart -> gather line sharing within the wave.
// - BRANCHLESS validity: all 16 taps loaded unconditionally from clamped
//   (always in-bounds) addresses, weighted by 0/1 mask. No exec-mask
//   branches -> compiler clusters all 16 gathers -> max per-thread MLP.
// - output is write-once: nontemporal store protects feature residency in L2/L3.

#define FC 256
#define FH 200
#define FW 200
#define NBIN 49   // 7*7
#define SCALE 0.25f

__global__ __launch_bounds__(256) void roi_align_fwd(
    const float* __restrict__ feat,
    const float* __restrict__ rois,
    float* __restrict__ out)
{
    const int n = blockIdx.y;                      // roi index (uniform)
    const int e = blockIdx.x * 256 + threadIdx.x;  // element within roi
    const int c   = e / NBIN;
    const int bin = e - c * NBIN;
    const int py  = bin / 7;
    const int px  = bin - py * 7;

    // Uniform -> scalar loads.
    const float* roi = rois + n * 5;
    const int   b  = (int)roi[0];
    const float x1 = roi[1] * SCALE;
    const float y1 = roi[2] * SCALE;
    const float x2 = roi[3] * SCALE;
    const float y2 = roi[4] * SCALE;
    const float bin_w = fmaxf(x2 - x1, 1.0f) * (1.0f / 7.0f);
    const float bin_h = fmaxf(y2 - y1, 1.0f) * (1.0f / 7.0f);

    const float* fp = feat + ((size_t)b * FC + c) * (FH * FW);

    // Per-sample metadata, computed branchlessly for all 4 samples first so
    // the 16 gathers can issue as one cluster.
    int   off[2][2];
    float wgt[2][2];   // validity (0/1) folded in
    float lyv[2], hyv[2], lxv[2], hxv[2];
    int   y0v[2], x0v[2];

    #pragma unroll
    for (int s = 0; s < 2; ++s) {
        float fy = ((float)(2 * py + s) + 0.5f) * 0.5f;
        float y  = fmaf(fy, bin_h, y1);
        float vy = ((y >= -1.0f) && (y <= (float)FH)) ? 1.0f : 0.0f;
        float yc = fminf(fmaxf(y, 0.0f), (float)(FH - 1));
        int   y0 = min((int)yc, FH - 2);
        lyv[s] = yc - (float)y0;
        hyv[s] = vy * (1.0f - lyv[s]);   // fold validity into hy,ly
        lyv[s] = vy * lyv[s];
        y0v[s] = y0;

        float fx = ((float)(2 * px + s) + 0.5f) * 0.5f;
        float x  = fmaf(fx, bin_w, x1);
        float vx = ((x >= -1.0f) && (x <= (float)FW)) ? 1.0f : 0.0f;
        float xc = fminf(fmaxf(x, 0.0f), (float)(FW - 1));
        int   x0 = min((int)xc, FW - 2);
        lxv[s] = xc - (float)x0;
        hxv[s] = vx * (1.0f - lxv[s]);
        lxv[s] = vx * lxv[s];
        x0v[s] = x0;
    }
    #pragma unroll
    for (int sy = 0; sy < 2; ++sy)
        #pragma unroll
        for (int sx = 0; sx < 2; ++sx)
            off[sy][sx] = y0v[sy] * FW + x0v[sx];

    // 16 unconditional gathers (4 per sample), then weighted reduce.
    float acc = 0.0f;
    #pragma unroll
    for (int sy = 0; sy < 2; ++sy) {
        #pragma unroll
        for (int sx = 0; sx < 2; ++sx) {
            const float* p0 = fp + off[sy][sx];
            float v00 = p0[0];
            float v01 = p0[1];
            float v10 = p0[FW];
            float v11 = p0[FW + 1];
            float top = fmaf(lxv[sx], v01, hxv[sx] * v00);
            float bot = fmaf(lxv[sx], v11, hxv[sx] * v10);
            acc += fmaf(hyv[sy], top, lyv[sy] * bot);
        }
    }
    __builtin_nontemporal_store(acc * 0.25f, &out[(size_t)n * (FC * NBIN) + e]);
}

extern "C" void kernel_launch(void* const* d_in, const int* in_sizes, int n_in,
                              void* d_out, int out_size, void* d_ws, size_t ws_size,
                              hipStream_t stream) {
    const float* feat = (const float*)d_in[0];
    const float* rois = (const float*)d_in[1];
    float* out = (float*)d_out;

    const int N = in_sizes[1] / 5;             // 1000
    dim3 grid(FC * NBIN / 256, N);             // (49, 1000)
    roi_align_fwd<<<grid, dim3(256), 0, stream>>>(feat, rois, out);
}

// Round 5
// 241.529 us; speedup vs baseline: 1.7263x; 1.7263x over previous
//
#include <hip/hip_runtime.h>

// RoIAlign forward, MI355X (gfx950). Two-pass:
//  1) transpose features NCHW -> NHWC into d_ws (82 MB), tiled via LDS.
//  2) gather with lanes across channels: every bilinear tap is a fully
//     contiguous 1 KB read (256 ch x 4B) -> 100% L2-line utilization,
//     vs ~8-16B/64B line in NCHW (measured: 1.19 GB FETCH @3.8 TB/s, 321 us).
// Bilinear metadata is wave-uniform (roi + bin are block-uniform) -> scalar.
// Output staged in LDS so final stores are coalesced (out layout is (n,c,7,7);
// direct per-bin stores would be stride-196B).

#define FC 256
#define FH 200
#define FW 200
#define NBIN 49
#define SCALE 0.25f
#define FS (FH * FW)          // 40000 spatial
#define PLANE (FC * NBIN)     // 12544 out elems per roi

// ---------- Pass 1: NCHW -> NHWC transpose (per batch: C x S -> S x C) ----
__global__ __launch_bounds__(256) void nchw_to_nhwc(
    const float* __restrict__ in,   // (B, C, S)
    float* __restrict__ out)        // (B, S, C)
{
    __shared__ float tile[32][33];
    const int b  = blockIdx.z;
    const int s0 = blockIdx.x * 32;
    const int c0 = blockIdx.y * 32;
    const float* ip = in  + (size_t)b * FC * FS;
    float*       op = out + (size_t)b * FS * FC;

    #pragma unroll
    for (int i = threadIdx.y; i < 32; i += 8)
        tile[i][threadIdx.x] =
            __builtin_nontemporal_load(&ip[(size_t)(c0 + i) * FS + s0 + threadIdx.x]);
    __syncthreads();
    #pragma unroll
    for (int i = threadIdx.y; i < 32; i += 8)
        op[(size_t)(s0 + i) * FC + c0 + threadIdx.x] = tile[threadIdx.x][i];
}

// ---------- Pass 2: RoIAlign on NHWC ------------------------------------
__global__ __launch_bounds__(256) void roi_align_nhwc(
    const float* __restrict__ fnhwc,  // (B, 200, 200, 256)
    const float* __restrict__ rois,
    float* __restrict__ out)          // (N, 256, 7, 7)
{
    __shared__ float sm[PLANE];       // 50176 B -> 3 blocks/CU
    const int n = blockIdx.x;
    const int t = threadIdx.x;        // channel

    const float* roi = rois + n * 5;  // uniform -> scalar loads
    const int   b  = (int)roi[0];
    const float x1 = roi[1] * SCALE;
    const float y1 = roi[2] * SCALE;
    const float x2 = roi[3] * SCALE;
    const float y2 = roi[4] * SCALE;
    const float bin_w = fmaxf(x2 - x1, 1.0f) * (1.0f / 7.0f);
    const float bin_h = fmaxf(y2 - y1, 1.0f) * (1.0f / 7.0f);
    const float* fb = fnhwc + (size_t)b * FS * FC;

    #pragma unroll 2
    for (int bin = 0; bin < NBIN; ++bin) {
        const int py = bin / 7;
        const int px = bin - py * 7;
        float acc = 0.0f;
        #pragma unroll
        for (int sy = 0; sy < 2; ++sy) {
            float fy = ((float)(2 * py + sy) + 0.5f) * 0.5f;
            float y  = fmaf(fy, bin_h, y1);
            float vy = ((y >= -1.0f) && (y <= (float)FH)) ? 1.0f : 0.0f;
            float yc = fminf(fmaxf(y, 0.0f), (float)(FH - 1));
            int   y0 = min((int)yc, FH - 2);
            float ly = yc - (float)y0;
            float hy = vy * (1.0f - ly);
            ly *= vy;
            #pragma unroll
            for (int sx = 0; sx < 2; ++sx) {
                float fx = ((float)(2 * px + sx) + 0.5f) * 0.5f;
                float x  = fmaf(fx, bin_w, x1);
                float vx = ((x >= -1.0f) && (x <= (float)FW)) ? 1.0f : 0.0f;
                float xc = fminf(fmaxf(x, 0.0f), (float)(FW - 1));
                int   x0 = min((int)xc, FW - 2);
                float lx = xc - (float)x0;
                float hx = vx * (1.0f - lx);
                lx *= vx;
                // 4 contiguous-channel taps, each 1 KB across the block
                const float* p = fb + ((size_t)(y0 * FW + x0)) * FC + t;
                float v00 = p[0];
                float v01 = p[FC];
                float v10 = p[FW * FC];
                float v11 = p[FW * FC + FC];
                acc += hy * fmaf(lx, v01, hx * v00) + ly * fmaf(lx, v11, hx * v10);
            }
        }
        sm[t * NBIN + bin] = acc * 0.25f;   // bank: (49t+bin)%32, 49 odd -> 2-way max
    }
    __syncthreads();
    const size_t base = (size_t)n * PLANE;
    #pragma unroll
    for (int k = 0; k < NBIN; ++k)
        __builtin_nontemporal_store(sm[t + k * FC], &out[base + t + k * FC]);
}

// ---------- Fallback (round-2 kernel) if ws too small --------------------
__global__ __launch_bounds__(256) void roi_align_nchw(
    const float* __restrict__ feat,
    const float* __restrict__ rois,
    float* __restrict__ out)
{
    const int n = blockIdx.y;
    const int e = blockIdx.x * 256 + threadIdx.x;
    const int c   = e / NBIN;
    const int bin = e - c * NBIN;
    const int py  = bin / 7;
    const int px  = bin - py * 7;

    const float* roi = rois + n * 5;
    const int   b  = (int)roi[0];
    const float x1 = roi[1] * SCALE;
    const float y1 = roi[2] * SCALE;
    const float x2 = roi[3] * SCALE;
    const float y2 = roi[4] * SCALE;
    const float bin_w = fmaxf(x2 - x1, 1.0f) * (1.0f / 7.0f);
    const float bin_h = fmaxf(y2 - y1, 1.0f) * (1.0f / 7.0f);
    const float* fp = feat + ((size_t)b * FC + c) * FS;

    float acc = 0.0f;
    #pragma unroll
    for (int sy = 0; sy < 2; ++sy) {
        float fy = ((float)(2 * py + sy) + 0.5f) * 0.5f;
        float y  = fmaf(fy, bin_h, y1);
        float vy = ((y >= -1.0f) && (y <= (float)FH)) ? 1.0f : 0.0f;
        float yc = fminf(fmaxf(y, 0.0f), (float)(FH - 1));
        int   y0 = min((int)yc, FH - 2);
        float ly = yc - (float)y0;
        float hy = vy * (1.0f - ly);
        ly *= vy;
        #pragma unroll
        for (int sx = 0; sx < 2; ++sx) {
            float fx = ((float)(2 * px + sx) + 0.5f) * 0.5f;
            float x  = fmaf(fx, bin_w, x1);
            float vx = ((x >= -1.0f) && (x <= (float)FW)) ? 1.0f : 0.0f;
            float xc = fminf(fmaxf(x, 0.0f), (float)(FW - 1));
            int   x0 = min((int)xc, FW - 2);
            float lx = xc - (float)x0;
            float hx = vx * (1.0f - lx);
            lx *= vx;
            const float* p0 = fp + y0 * FW + x0;
            acc += hy * fmaf(lx, p0[1], hx * p0[0])
                 + ly * fmaf(lx, p0[FW + 1], hx * p0[FW]);
        }
    }
    __builtin_nontemporal_store(acc * 0.25f, &out[(size_t)n * PLANE + e]);
}

extern "C" void kernel_launch(void* const* d_in, const int* in_sizes, int n_in,
                              void* d_out, int out_size, void* d_ws, size_t ws_size,
                              hipStream_t stream) {
    const float* feat = (const float*)d_in[0];
    const float* rois = (const float*)d_in[1];
    float* out = (float*)d_out;
    const int N = in_sizes[1] / 5;               // 1000

    const size_t need = (size_t)2 * FC * FS * sizeof(float);  // 81.92 MB
    if (ws_size >= need) {
        float* fnhwc = (float*)d_ws;
        dim3 tg(FS / 32, FC / 32, 2);            // (1250, 8, 2)
        nchw_to_nhwc<<<tg, dim3(32, 8), 0, stream>>>(feat, fnhwc);
        roi_align_nhwc<<<dim3(N), dim3(256), 0, stream>>>(fnhwc, rois, out);
    } else {
        dim3 grid(PLANE / 256, N);
        roi_align_nchw<<<grid, dim3(256), 0, stream>>>(feat, rois, out);
    }
}

// Round 7
// 230.919 us; speedup vs baseline: 1.8056x; 1.0459x over previous
//
#include <hip/hip_runtime.h>

// RoIAlign forward, MI355X (gfx950). Two-pass, both passes float4-vectorized.
//  1) NCHW -> NHWC transpose into d_ws (82 MB): 64s x 256c LDS tile,
//     float4 global loads+stores, XOR-swizzled LDS (<=2-way conflicts).
//  2) gather on NHWC: one wave (64 lanes x float4) covers all 256 channels
//     of a bilinear tap in one 1KB coalesced burst; 4 waves split the 49
//     bins. 16 in-flight float4 loads per lane per bin (latency cover).
// Round-5 measurement: gather = 98.6us @ 294MB fetch (3 TB/s, VALUBusy 22%,
// occ 24%) -> latency-bound scalar loads; transpose ~100+us scalar accesses.
// NOTE: __builtin_nontemporal_* needs a NATIVE vector type, not
// HIP_vector_type -> use ext_vector_type alias (round-6 compile fix).

#define FC 256
#define FH 200
#define FW 200
#define NBIN 49
#define SCALE 0.25f
#define FS (FH * FW)          // 40000 spatial
#define PLANE (FC * NBIN)     // 12544 out elems per roi

typedef float vf4 __attribute__((ext_vector_type(4)));

// ---------- Pass 1: NCHW -> NHWC transpose, float4 both sides ------------
__global__ __launch_bounds__(256) void nchw_to_nhwc(
    const float* __restrict__ in,   // (B, C, S)
    float* __restrict__ out)        // (B, S, C)
{
    __shared__ float tile[64 * FC];            // 64 KB
    const int b  = blockIdx.y;
    const int s0 = blockIdx.x * 64;
    const float* ip = in  + (size_t)b * FC * FS;
    float*       op = out + (size_t)b * FS * FC;
    const int t  = threadIdx.x;
    const int tx = t & 15;                     // spatial chunk (4 floats)
    const int ty = t >> 4;                     // channel row within group
    const int X  = (tx & 7) << 2;              // swizzle for s = 4*tx + j

    #pragma unroll
    for (int r = 0; r < FC; r += 16) {
        const int c = r + ty;
        vf4 v = __builtin_nontemporal_load(
            (const vf4*)&ip[(size_t)c * FS + s0 + 4 * tx]);
        const int cs = c ^ X;                  // phys column (swizzled)
        const int s  = 4 * tx;
        tile[(s + 0) * FC + cs] = v.x;
        tile[(s + 1) * FC + cs] = v.y;
        tile[(s + 2) * FC + cs] = v.z;
        tile[(s + 3) * FC + cs] = v.w;
    }
    __syncthreads();
    const int lane = t & 63, wv = t >> 6;
    #pragma unroll
    for (int r = 0; r < 64; r += 4) {
        const int s  = r + wv;
        const int Xs = ((s >> 2) & 7) << 2;    // matches write-side X
        vf4 v = *(const vf4*)&tile[s * FC + ((4 * lane) ^ Xs)];
        *(vf4*)&op[(size_t)(s0 + s) * FC + 4 * lane] = v;
    }
}

// ---------- Pass 2: RoIAlign on NHWC, float4 channel vectorization -------
__global__ __launch_bounds__(256, 3) void roi_align_nhwc(
    const float* __restrict__ fnhwc,  // (B, 200, 200, 256)
    const float* __restrict__ rois,
    float* __restrict__ out)          // (N, 256, 7, 7)
{
    __shared__ float sm[PLANE];       // 50176 B -> 3 blocks/CU
    const int n    = blockIdx.x;
    const int t    = threadIdx.x;
    const int lane = t & 63;          // 64 lanes x 4ch = 256 channels
    const int wv   = t >> 6;          // wave id: bins wv, wv+4, ...

    const float* roi = rois + n * 5;  // uniform -> scalar loads
    const int   b  = (int)roi[0];
    const float x1 = roi[1] * SCALE;
    const float y1 = roi[2] * SCALE;
    const float x2 = roi[3] * SCALE;
    const float y2 = roi[4] * SCALE;
    const float bin_w = fmaxf(x2 - x1, 1.0f) * (1.0f / 7.0f);
    const float bin_h = fmaxf(y2 - y1, 1.0f) * (1.0f / 7.0f);
    const vf4* fb4 = (const vf4*)(fnhwc + (size_t)b * FS * FC);

    for (int bin = wv; bin < NBIN; bin += 4) {
        const int py = bin / 7;
        const int px = bin - py * 7;
        float ax = 0.0f, ay = 0.0f, az = 0.0f, aw = 0.0f;
        #pragma unroll
        for (int sy = 0; sy < 2; ++sy) {
            float fy = ((float)(2 * py + sy) + 0.5f) * 0.5f;
            float y  = fmaf(fy, bin_h, y1);
            float vy = ((y >= -1.0f) && (y <= (float)FH)) ? 1.0f : 0.0f;
            float yc = fminf(fmaxf(y, 0.0f), (float)(FH - 1));
            int   y0 = min((int)yc, FH - 2);
            float ly = yc - (float)y0;
            float hy = vy * (1.0f - ly);
            ly *= vy;
            #pragma unroll
            for (int sx = 0; sx < 2; ++sx) {
                float fx = ((float)(2 * px + sx) + 0.5f) * 0.5f;
                float x  = fmaf(fx, bin_w, x1);
                float vx = ((x >= -1.0f) && (x <= (float)FW)) ? 1.0f : 0.0f;
                float xc = fminf(fmaxf(x, 0.0f), (float)(FW - 1));
                int   x0 = min((int)xc, FW - 2);
                float lx = xc - (float)x0;
                float hx = vx * (1.0f - lx);
                lx *= vx;
                // 4 taps, each a wave-wide 1KB contiguous burst
                const vf4* p = fb4 + (size_t)(y0 * FW + x0) * 64 + lane;
                vf4 v00 = p[0];
                vf4 v01 = p[64];
                vf4 v10 = p[(size_t)FW * 64];
                vf4 v11 = p[(size_t)FW * 64 + 64];
                float wa = hy * hx, wb = hy * lx, wc = ly * hx, wd = ly * lx;
                ax += fmaf(wa, v00.x, fmaf(wb, v01.x, fmaf(wc, v10.x, wd * v11.x)));
                ay += fmaf(wa, v00.y, fmaf(wb, v01.y, fmaf(wc, v10.y, wd * v11.y)));
                az += fmaf(wa, v00.z, fmaf(wb, v01.z, fmaf(wc, v10.z, wd * v11.z)));
                aw += fmaf(wa, v00.w, fmaf(wb, v01.w, fmaf(wc, v10.w, wd * v11.w)));
            }
        }
        const int c0 = 4 * lane;
        sm[(c0 + 0) * NBIN + bin] = ax * 0.25f;   // (c,bin) layout = out order
        sm[(c0 + 1) * NBIN + bin] = ay * 0.25f;
        sm[(c0 + 2) * NBIN + bin] = az * 0.25f;
        sm[(c0 + 3) * NBIN + bin] = aw * 0.25f;
    }
    __syncthreads();
    // identity copy sm -> out, float4 coalesced
    vf4* out4 = (vf4*)(out + (size_t)n * PLANE);
    for (int i = t; i < PLANE / 4; i += 256) {
        vf4 v = *(const vf4*)&sm[4 * i];
        __builtin_nontemporal_store(v, &out4[i]);
    }
}

// ---------- Fallback (round-2 kernel) if ws too small --------------------
__global__ __launch_bounds__(256) void roi_align_nchw(
    const float* __restrict__ feat,
    const float* __restrict__ rois,
    float* __restrict__ out)
{
    const int n = blockIdx.y;
    const int e = blockIdx.x * 256 + threadIdx.x;
    const int c   = e / NBIN;
    const int bin = e - c * NBIN;
    const int py  = bin / 7;
    const int px  = bin - py * 7;

    const float* roi = rois + n * 5;
    const int   b  = (int)roi[0];
    const float x1 = roi[1] * SCALE;
    const float y1 = roi[2] * SCALE;
    const float x2 = roi[3] * SCALE;
    const float y2 = roi[4] * SCALE;
    const float bin_w = fmaxf(x2 - x1, 1.0f) * (1.0f / 7.0f);
    const float bin_h = fmaxf(y2 - y1, 1.0f) * (1.0f / 7.0f);
    const float* fp = feat + ((size_t)b * FC + c) * FS;

    float acc = 0.0f;
    #pragma unroll
    for (int sy = 0; sy < 2; ++sy) {
        float fy = ((float)(2 * py + sy) + 0.5f) * 0.5f;
        float y  = fmaf(fy, bin_h, y1);
        float vy = ((y >= -1.0f) && (y <= (float)FH)) ? 1.0f : 0.0f;
        float yc = fminf(fmaxf(y, 0.0f), (float)(FH - 1));
        int   y0 = min((int)yc, FH - 2);
        float ly = yc - (float)y0;
        float hy = vy * (1.0f - ly);
        ly *= vy;
        #pragma unroll
        for (int sx = 0; sx < 2; ++sx) {
            float fx = ((float)(2 * px + sx) + 0.5f) * 0.5f;
            float x  = fmaf(fx, bin_w, x1);
            float vx = ((x >= -1.0f) && (x <= (float)FW)) ? 1.0f : 0.0f;
            float xc = fminf(fmaxf(x, 0.0f), (float)(FW - 1));
            int   x0 = min((int)xc, FW - 2);
            float lx = xc - (float)x0;
            float hx = vx * (1.0f - lx);
            lx *= vx;
            const float* p0 = fp + y0 * FW + x0;
            acc += hy * fmaf(lx, p0[1], hx * p0[0])
                 + ly * fmaf(lx, p0[FW + 1], hx * p0[FW]);
        }
    }
    __builtin_nontemporal_store(acc * 0.25f, &out[(size_t)n * PLANE + e]);
}

extern "C" void kernel_launch(void* const* d_in, const int* in_sizes, int n_in,
                              void* d_out, int out_size, void* d_ws, size_t ws_size,
                              hipStream_t stream) {
    const float* feat = (const float*)d_in[0];
    const float* rois = (const float*)d_in[1];
    float* out = (float*)d_out;
    const int N = in_sizes[1] / 5;               // 1000

    const size_t need = (size_t)2 * FC * FS * sizeof(float);  // 81.92 MB
    if (ws_size >= need) {
        float* fnhwc = (float*)d_ws;
        dim3 tg(FS / 64, 2);                     // (625, 2)
        nchw_to_nhwc<<<tg, dim3(256), 0, stream>>>(feat, fnhwc);
        roi_align_nhwc<<<dim3(N), dim3(256), 0, stream>>>(fnhwc, rois, out);
    } else {
        dim3 grid(PLANE / 256, N);
        roi_align_nchw<<<grid, dim3(256), 0, stream>>>(feat, rois, out);
    }
}

// Round 10
// 174.881 us; speedup vs baseline: 2.3842x; 1.3204x over previous
//
#include <hip/hip_runtime.h>

// RoIAlign forward, MI355X (gfx950). Two-pass with FP16 NHWC staging.
//  1) NCHW(fp32) -> NHWC(fp16) transpose into d_ws (41 MB).
//  2) gather on fp16 NHWC: each bilinear tap = 512B wave burst (8B/lane).
// Round-7 finding: float4 gather was NEUTRAL (96.4us, 293MB, 3.0 TB/s both
// rounds) -> gather is MSHR/outstanding-line x latency bound, not issue
// bound. Halving bytes/tap doubles taps-in-flight at the same wall.
// absmax is quantized at 2^-7 across all fp32 kernels -> fp16's <=2.4e-3
// added error stays within ~1 quantum.

#define FC 256
#define FH 200
#define FW 200
#define NBIN 49
#define SCALE 0.25f
#define FS (FH * FW)          // 40000 spatial
#define PLANE (FC * NBIN)     // 12544 out elems per roi

typedef float vf4 __attribute__((ext_vector_type(4)));
typedef _Float16 vh4 __attribute__((ext_vector_type(4)));   // 8 bytes

// ---------- Pass 1: NCHW fp32 -> NHWC fp16 -------------------------------
__global__ __launch_bounds__(256) void nchw_to_nhwc_h(
    const float* __restrict__ in,     // (B, C, S) fp32
    _Float16* __restrict__ out)       // (B, S, C) fp16
{
    __shared__ float tile[64 * FC];            // 64 KB
    const int b  = blockIdx.y;
    const int s0 = blockIdx.x * 64;
    const float* ip = in  + (size_t)b * FC * FS;
    _Float16*    op = out + (size_t)b * FS * FC;
    const int t  = threadIdx.x;
    const int tx = t & 15;                     // spatial chunk (4 floats)
    const int ty = t >> 4;                     // channel row within group
    const int X  = (tx & 7) << 2;              // swizzle for s = 4*tx + j

    #pragma unroll
    for (int r = 0; r < FC; r += 16) {
        const int c = r + ty;
        vf4 v = __builtin_nontemporal_load(
            (const vf4*)&ip[(size_t)c * FS + s0 + 4 * tx]);
        const int cs = c ^ X;                  // phys column (swizzled)
        const int s  = 4 * tx;
        tile[(s + 0) * FC + cs] = v.x;
        tile[(s + 1) * FC + cs] = v.y;
        tile[(s + 2) * FC + cs] = v.z;
        tile[(s + 3) * FC + cs] = v.w;
    }
    __syncthreads();
    const int lane = t & 63, wv = t >> 6;
    #pragma unroll
    for (int r = 0; r < 64; r += 4) {
        const int s  = r + wv;
        const int Xs = ((s >> 2) & 7) << 2;    // matches write-side X
        vf4 v = *(const vf4*)&tile[s * FC + ((4 * lane) ^ Xs)];
        vh4 h;
        h.x = (_Float16)v.x; h.y = (_Float16)v.y;
        h.z = (_Float16)v.z; h.w = (_Float16)v.w;
        *(vh4*)&op[(size_t)(s0 + s) * FC + 4 * lane] = h;   // 512B/row burst
    }
}

// ---------- Pass 2: RoIAlign gather on fp16 NHWC -------------------------
__global__ __launch_bounds__(256, 3) void roi_align_h(
    const _Float16* __restrict__ fh,  // (B, 200, 200, 256) fp16
    const float* __restrict__ rois,
    float* __restrict__ out)          // (N, 256, 7, 7) fp32
{
    __shared__ float sm[PLANE];       // 50176 B -> 3 blocks/CU
    const int n    = blockIdx.x;
    const int t    = threadIdx.x;
    const int lane = t & 63;          // 64 lanes x 4ch = 256 channels
    const int wv   = t >> 6;          // wave id: bins wv, wv+4, ...

    const float* roi = rois + n * 5;  // uniform -> scalar loads
    const int   b  = (int)roi[0];
    const float x1 = roi[1] * SCALE;
    const float y1 = roi[2] * SCALE;
    const float x2 = roi[3] * SCALE;
    const float y2 = roi[4] * SCALE;
    const float bin_w = fmaxf(x2 - x1, 1.0f) * (1.0f / 7.0f);
    const float bin_h = fmaxf(y2 - y1, 1.0f) * (1.0f / 7.0f);
    const vh4* fb = (const vh4*)(fh + (size_t)b * FS * FC);  // FC/4=64 vh4/loc

    #pragma unroll 2
    for (int bin = wv; bin < NBIN; bin += 4) {
        const int py = bin / 7;
        const int px = bin - py * 7;
        vf4 acc = {0.0f, 0.0f, 0.0f, 0.0f};
        #pragma unroll
        for (int sy = 0; sy < 2; ++sy) {
            float fy = ((float)(2 * py + sy) + 0.5f) * 0.5f;
            float y  = fmaf(fy, bin_h, y1);
            float vy = ((y >= -1.0f) && (y <= (float)FH)) ? 1.0f : 0.0f;
            float yc = fminf(fmaxf(y, 0.0f), (float)(FH - 1));
            int   y0 = min((int)yc, FH - 2);
            float ly = yc - (float)y0;
            float hy = vy * (1.0f - ly);
            ly *= vy;
            #pragma unroll
            for (int sx = 0; sx < 2; ++sx) {
                float fx = ((float)(2 * px + sx) + 0.5f) * 0.5f;
                float x  = fmaf(fx, bin_w, x1);
                float vx = ((x >= -1.0f) && (x <= (float)FW)) ? 1.0f : 0.0f;
                float xc = fminf(fmaxf(x, 0.0f), (float)(FW - 1));
                int   x0 = min((int)xc, FW - 2);
                float lx = xc - (float)x0;
                float hx = vx * (1.0f - lx);
                lx *= vx;
                // 4 taps, each a wave-wide 512B contiguous burst (8B/lane)
                const vh4* p = fb + (size_t)(y0 * FW + x0) * 64 + lane;
                vh4 v00 = p[0];
                vh4 v01 = p[64];
                vh4 v10 = p[(size_t)FW * 64];
                vh4 v11 = p[(size_t)FW * 64 + 64];
                float wa = hy * hx, wb = hy * lx, wc = ly * hx, wd = ly * lx;
                acc += wa * __builtin_convertvector(v00, vf4)
                     + wb * __builtin_convertvector(v01, vf4)
                     + wc * __builtin_convertvector(v10, vf4)
                     + wd * __builtin_convertvector(v11, vf4);
            }
        }
        const int c0 = 4 * lane;
        sm[(c0 + 0) * NBIN + bin] = acc.x * 0.25f;   // (c,bin) = out order
        sm[(c0 + 1) * NBIN + bin] = acc.y * 0.25f;
        sm[(c0 + 2) * NBIN + bin] = acc.z * 0.25f;
        sm[(c0 + 3) * NBIN + bin] = acc.w * 0.25f;
    }
    __syncthreads();
    // identity copy sm -> out, float4 coalesced
    vf4* out4 = (vf4*)(out + (size_t)n * PLANE);
    for (int i = t; i < PLANE / 4; i += 256) {
        vf4 v = *(const vf4*)&sm[4 * i];
        __builtin_nontemporal_store(v, &out4[i]);
    }
}

// ---------- Fallback (fp32 NCHW, no workspace) ---------------------------
__global__ __launch_bounds__(256) void roi_align_nchw(
    const float* __restrict__ feat,
    const float* __restrict__ rois,
    float* __restrict__ out)
{
    const int n = blockIdx.y;
    const int e = blockIdx.x * 256 + threadIdx.x;
    const int c   = e / NBIN;
    const int bin = e - c * NBIN;
    const int py  = bin / 7;
    const int px  = bin - py * 7;

    const float* roi = rois + n * 5;
    const int   b  = (int)roi[0];
    const float x1 = roi[1] * SCALE;
    const float y1 = roi[2] * SCALE;
    const float x2 = roi[3] * SCALE;
    const float y2 = roi[4] * SCALE;
    const float bin_w = fmaxf(x2 - x1, 1.0f) * (1.0f / 7.0f);
    const float bin_h = fmaxf(y2 - y1, 1.0f) * (1.0f / 7.0f);
    const float* fp = feat + ((size_t)b * FC + c) * FS;

    float acc = 0.0f;
    #pragma unroll
    for (int sy = 0; sy < 2; ++sy) {
        float fy = ((float)(2 * py + sy) + 0.5f) * 0.5f;
        float y  = fmaf(fy, bin_h, y1);
        float vy = ((y >= -1.0f) && (y <= (float)FH)) ? 1.0f : 0.0f;
        float yc = fminf(fmaxf(y, 0.0f), (float)(FH - 1));
        int   y0 = min((int)yc, FH - 2);
        float ly = yc - (float)y0;
        float hy = vy * (1.0f - ly);
        ly *= vy;
        #pragma unroll
        for (int sx = 0; sx < 2; ++sx) {
            float fx = ((float)(2 * px + sx) + 0.5f) * 0.5f;
            float x  = fmaf(fx, bin_w, x1);
            float vx = ((x >= -1.0f) && (x <= (float)FW)) ? 1.0f : 0.0f;
            float xc = fminf(fmaxf(x, 0.0f), (float)(FW - 1));
            int   x0 = min((int)xc, FW - 2);
            float lx = xc - (float)x0;
            float hx = vx * (1.0f - lx);
            lx *= vx;
            const float* p0 = fp + y0 * FW + x0;
            acc += hy * fmaf(lx, p0[1], hx * p0[0])
                 + ly * fmaf(lx, p0[FW + 1], hx * p0[FW]);
        }
    }
    __builtin_nontemporal_store(acc * 0.25f, &out[(size_t)n * PLANE + e]);
}

extern "C" void kernel_launch(void* const* d_in, const int* in_sizes, int n_in,
                              void* d_out, int out_size, void* d_ws, size_t ws_size,
                              hipStream_t stream) {
    const float* feat = (const float*)d_in[0];
    const float* rois = (const float*)d_in[1];
    float* out = (float*)d_out;
    const int N = in_sizes[1] / 5;               // 1000

    const size_t need = (size_t)2 * FC * FS * sizeof(_Float16);  // 41 MB
    if (ws_size >= need) {
        _Float16* fh = (_Float16*)d_ws;
        dim3 tg(FS / 64, 2);                     // (625, 2)
        nchw_to_nhwc_h<<<tg, dim3(256), 0, stream>>>(feat, fh);
        roi_align_h<<<dim3(N), dim3(256), 0, stream>>>(fh, rois, out);
    } else {
        dim3 grid(PLANE / 256, N);
        roi_align_nchw<<<grid, dim3(256), 0, stream>>>(feat, rois, out);
    }
}

// Round 12
// 174.044 us; speedup vs baseline: 2.3957x; 1.0048x over previous
//
#include <hip/hip_runtime.h>

// RoIAlign forward, MI355X (gfx950). Two-pass, fp16 NHWC staging.
//  1) NCHW(fp32) -> NHWC(fp16) transpose into d_ws (41 MB).   (~30us)
//  2) gather: grid (N, 2 channel-halves). Each block: 128 channels x 49
//     bins, tap = 256B wave burst (1 dword/lane), 25KB LDS staging ->
//     6 blocks/CU (was 3 at 50KB), ~24 waves/CU.
// R10 measured: gather 49.4us, 133MB fetch (2.7 TB/s), occ 22% -> latency
// bound on wave count, not request width (R7) nor bytes (R10 halving bytes
// halved time). This round buys occupancy with smaller LDS per block.
// absmax quantum is 2^-7; fp16 staging measured absmax 0.015625, passing.

#define FC 256
#define FH 200
#define FW 200
#define NBIN 49
#define SCALE 0.25f
#define FS (FH * FW)          // 40000 spatial
#define PLANE (FC * NBIN)     // 12544 out elems per roi
#define HCH 128               // channels per gather block
#define HPLANE (HCH * NBIN)   // 6272 floats = 25088 B LDS

typedef float vf4 __attribute__((ext_vector_type(4)));
typedef _Float16 vh4 __attribute__((ext_vector_type(4)));
typedef _Float16 vh2 __attribute__((ext_vector_type(2)));

// ---------- Pass 1: NCHW fp32 -> NHWC fp16 (unchanged from R10) ----------
__global__ __launch_bounds__(256) void nchw_to_nhwc_h(
    const float* __restrict__ in,     // (B, C, S) fp32
    _Float16* __restrict__ out)       // (B, S, C) fp16
{
    __shared__ float tile[64 * FC];            // 64 KB
    const int b  = blockIdx.y;
    const int s0 = blockIdx.x * 64;
    const float* ip = in  + (size_t)b * FC * FS;
    _Float16*    op = out + (size_t)b * FS * FC;
    const int t  = threadIdx.x;
    const int tx = t & 15;                     // spatial chunk (4 floats)
    const int ty = t >> 4;                     // channel row within group
    const int X  = (tx & 7) << 2;              // swizzle for s = 4*tx + j

    #pragma unroll
    for (int r = 0; r < FC; r += 16) {
        const int c = r + ty;
        vf4 v = __builtin_nontemporal_load(
            (const vf4*)&ip[(size_t)c * FS + s0 + 4 * tx]);
        const int cs = c ^ X;                  // phys column (swizzled)
        const int s  = 4 * tx;
        tile[(s + 0) * FC + cs] = v.x;
        tile[(s + 1) * FC + cs] = v.y;
        tile[(s + 2) * FC + cs] = v.z;
        tile[(s + 3) * FC + cs] = v.w;
    }
    __syncthreads();
    const int lane = t & 63, wv = t >> 6;
    #pragma unroll
    for (int r = 0; r < 64; r += 4) {
        const int s  = r + wv;
        const int Xs = ((s >> 2) & 7) << 2;    // matches write-side X
        vf4 v = *(const vf4*)&tile[s * FC + ((4 * lane) ^ Xs)];
        vh4 h;
        h.x = (_Float16)v.x; h.y = (_Float16)v.y;
        h.z = (_Float16)v.z; h.w = (_Float16)v.w;
        *(vh4*)&op[(size_t)(s0 + s) * FC + 4 * lane] = h;   // 512B/row burst
    }
}

// ---------- Pass 2: gather, 2 channel-half blocks per roi ----------------
__global__ __launch_bounds__(256, 6) void roi_align_h(
    const _Float16* __restrict__ fh,  // (B, 200, 200, 256) fp16
    const float* __restrict__ rois,
    float* __restrict__ out)          // (N, 256, 7, 7) fp32
{
    __shared__ float sm[HPLANE];      // 25088 B -> 6 blocks/CU
    const int n    = blockIdx.x;
    const int half = blockIdx.y;      // channel half: 0 or 1
    const int t    = threadIdx.x;
    const int lane = t & 63;          // 64 lanes x 2ch = 128 channels
    const int wv   = t >> 6;          // wave id: bins wv, wv+4, ...

    const float* roi = rois + n * 5;  // uniform -> scalar loads
    const int   b  = (int)roi[0];
    const float x1 = roi[1] * SCALE;
    const float y1 = roi[2] * SCALE;
    const float x2 = roi[3] * SCALE;
    const float y2 = roi[4] * SCALE;
    const float bin_w = fmaxf(x2 - x1, 1.0f) * (1.0f / 7.0f);
    const float bin_h = fmaxf(y2 - y1, 1.0f) * (1.0f / 7.0f);
    // position record = 512B = 128 vh2; this block reads vh2 #(half*64+lane)
    const vh2* fb = (const vh2*)(fh + (size_t)b * FS * FC) + half * 64 + lane;

    #pragma unroll 2
    for (int bin = wv; bin < NBIN; bin += 4) {
        const int py = bin / 7;
        const int px = bin - py * 7;
        float ax = 0.0f, ay = 0.0f;
        #pragma unroll
        for (int sy = 0; sy < 2; ++sy) {
            float fy = ((float)(2 * py + sy) + 0.5f) * 0.5f;
            float y  = fmaf(fy, bin_h, y1);
            float vy = ((y >= -1.0f) && (y <= (float)FH)) ? 1.0f : 0.0f;
            float yc = fminf(fmaxf(y, 0.0f), (float)(FH - 1));
            int   y0 = min((int)yc, FH - 2);
            float ly = yc - (float)y0;
            float hy = vy * (1.0f - ly);
            ly *= vy;
            #pragma unroll
            for (int sx = 0; sx < 2; ++sx) {
                float fx = ((float)(2 * px + sx) + 0.5f) * 0.5f;
                float x  = fmaf(fx, bin_w, x1);
                float vx = ((x >= -1.0f) && (x <= (float)FW)) ? 1.0f : 0.0f;
                float xc = fminf(fmaxf(x, 0.0f), (float)(FW - 1));
                int   x0 = min((int)xc, FW - 2);
                float lx = xc - (float)x0;
                float hx = vx * (1.0f - lx);
                lx *= vx;
                // 4 taps, each a wave-wide 256B burst (4B/lane)
                const vh2* p = fb + (size_t)(y0 * FW + x0) * 128;
                vh2 v00 = p[0];
                vh2 v01 = p[128];
                vh2 v10 = p[(size_t)FW * 128];
                vh2 v11 = p[(size_t)FW * 128 + 128];
                float wa = hy * hx, wb = hy * lx, wc = ly * hx, wd = ly * lx;
                ax += fmaf(wa, (float)v00.x, fmaf(wb, (float)v01.x,
                      fmaf(wc, (float)v10.x, wd * (float)v11.x)));
                ay += fmaf(wa, (float)v00.y, fmaf(wb, (float)v01.y,
                      fmaf(wc, (float)v10.y, wd * (float)v11.y)));
            }
        }
        const int c0 = 2 * lane;      // local channel
        sm[(c0 + 0) * NBIN + bin] = ax * 0.25f;   // (c,bin) = out order
        sm[(c0 + 1) * NBIN + bin] = ay * 0.25f;
    }
    __syncthreads();
    // half-plane is a CONTIGUOUS 25KB range of out -> float4 coalesced copy
    vf4* out4 = (vf4*)(out + (size_t)n * PLANE + (size_t)half * HPLANE);
    for (int i = t; i < HPLANE / 4; i += 256) {
        vf4 v = *(const vf4*)&sm[4 * i];
        __builtin_nontemporal_store(v, &out4[i]);
    }
}

// ---------- Fallback (fp32 NCHW, no workspace) ---------------------------
__global__ __launch_bounds__(256) void roi_align_nchw(
    const float* __restrict__ feat,
    const float* __restrict__ rois,
    float* __restrict__ out)
{
    const int n = blockIdx.y;
    const int e = blockIdx.x * 256 + threadIdx.x;
    const int c   = e / NBIN;
    const int bin = e - c * NBIN;
    const int py  = bin / 7;
    const int px  = bin - py * 7;

    const float* roi = rois + n * 5;
    const int   b  = (int)roi[0];
    const float x1 = roi[1] * SCALE;
    const float y1 = roi[2] * SCALE;
    const float x2 = roi[3] * SCALE;
    const float y2 = roi[4] * SCALE;
    const float bin_w = fmaxf(x2 - x1, 1.0f) * (1.0f / 7.0f);
    const float bin_h = fmaxf(y2 - y1, 1.0f) * (1.0f / 7.0f);
    const float* fp = feat + ((size_t)b * FC + c) * FS;

    float acc = 0.0f;
    #pragma unroll
    for (int sy = 0; sy < 2; ++sy) {
        float fy = ((float)(2 * py + sy) + 0.5f) * 0.5f;
        float y  = fmaf(fy, bin_h, y1);
        float vy = ((y >= -1.0f) && (y <= (float)FH)) ? 1.0f : 0.0f;
        float yc = fminf(fmaxf(y, 0.0f), (float)(FH - 1));
        int   y0 = min((int)yc, FH - 2);
        float ly = yc - (float)y0;
        float hy = vy * (1.0f - ly);
        ly *= vy;
        #pragma unroll
        for (int sx = 0; sx < 2; ++sx) {
            float fx = ((float)(2 * px + sx) + 0.5f) * 0.5f;
            float x  = fmaf(fx, bin_w, x1);
            float vx = ((x >= -1.0f) && (x <= (float)FW)) ? 1.0f : 0.0f;
            float xc = fminf(fmaxf(x, 0.0f), (float)(FW - 1));
            int   x0 = min((int)xc, FW - 2);
            float lx = xc - (float)x0;
            float hx = vx * (1.0f - lx);
            lx *= vx;
            const float* p0 = fp + y0 * FW + x0;
            acc += hy * fmaf(lx, p0[1], hx * p0[0])
                 + ly * fmaf(lx, p0[FW + 1], hx * p0[FW]);
        }
    }
    __builtin_nontemporal_store(acc * 0.25f, &out[(size_t)n * PLANE + e]);
}

extern "C" void kernel_launch(void* const* d_in, const int* in_sizes, int n_in,
                              void* d_out, int out_size, void* d_ws, size_t ws_size,
                              hipStream_t stream) {
    const float* feat = (const float*)d_in[0];
    const float* rois = (const float*)d_in[1];
    float* out = (float*)d_out;
    const int N = in_sizes[1] / 5;               // 1000

    const size_t need = (size_t)2 * FC * FS * sizeof(_Float16);  // 41 MB
    if (ws_size >= need) {
        _Float16* fh = (_Float16*)d_ws;
        dim3 tg(FS / 64, 2);                     // (625, 2)
        nchw_to_nhwc_h<<<tg, dim3(256), 0, stream>>>(feat, fh);
        roi_align_h<<<dim3(N, 2), dim3(256), 0, stream>>>(fh, rois, out);
    } else {
        dim3 grid(PLANE / 256, N);
        roi_align_nchw<<<grid, dim3(256), 0, stream>>>(feat, rois, out);
    }
}